// Round 4
// baseline (1724.457 us; speedup 1.0000x reference)
//
#include <hip/hip_runtime.h>
#include <hip/hip_bf16.h>

typedef _Float16 half2_t __attribute__((ext_vector_type(2)));
typedef _Float16 f16x8   __attribute__((ext_vector_type(8)));
typedef float    f32x4   __attribute__((ext_vector_type(4)));
typedef unsigned short u16;
typedef unsigned int   u32;

#define N_NODES 65536
#define IN_DIM  256
#define HIDDEN  256
#define G3      768     // 3*HIDDEN gate rows
#define NGRAPH  128

__device__ __forceinline__ float sigf(float x)    { return 1.f / (1.f + __expf(-x)); }
__device__ __forceinline__ float tanhfast(float x){ return 2.f / (1.f + __expf(-2.f * x)) - 1.f; }

// ---- per-graph starts via binary search on sorted batch.
// Handles both int32 and int64 on-device encodings: for int64 (LE, values<2^31)
// the int32 view has high word 0 at view[n-1]; for int32 view[n-1]==max id !=0.
__global__ void k_starts(const int* __restrict__ batch, int* __restrict__ starts, int n, int ngraph) {
    int g = blockIdx.x * blockDim.x + threadIdx.x;
    if (g > ngraph) return;
    int stride = (batch[n - 1] == 0) ? 2 : 1;
    if (g == ngraph) { starts[g] = n; return; }
    int lo = 0, hi = n;
    while (lo < hi) { int mid = (lo + hi) >> 1; if (batch[(size_t)mid * stride] < g) lo = mid + 1; else hi = mid; }
    starts[g] = lo;
}

// ---- f32 -> f16 elementwise (n multiple of 8) ----
__global__ void k_cvt8(const float* __restrict__ s, u16* __restrict__ d, int n) {
    int t = blockIdx.x * 256 + threadIdx.x;
    int i = t * 8;
    if (i >= n) return;
    float4 a = ((const float4*)(s + i))[0];
    float4 b = ((const float4*)(s + i))[1];
    f16x8 o;
    o[0] = (_Float16)a.x; o[1] = (_Float16)a.y; o[2] = (_Float16)a.z; o[3] = (_Float16)a.w;
    o[4] = (_Float16)b.x; o[5] = (_Float16)b.y; o[6] = (_Float16)b.z; o[7] = (_Float16)b.w;
    *(f16x8*)(d + i) = o;
}

// ---- W_hh f32 [768][256] -> swizzled f16 chunks so k_rec's register fill is
// coalesced. chunk t = w*2048 + i*64 + l holds W_hh[row=64w+l][8i..8i+7]. ----
__global__ void k_swz(const float* __restrict__ W, uint4* __restrict__ out) {
    int t = blockIdx.x * 256 + threadIdx.x;
    if (t >= 24576) return;
    int l = t & 63, i = (t >> 6) & 31, w = t >> 11;
    int row = w * 64 + l, col = i * 8;
    const float* s = W + row * 256 + col;
    f16x8 o;
#pragma unroll
    for (int q = 0; q < 8; q++) o[q] = (_Float16)s[q];
    out[t] = __builtin_bit_cast(uint4, o);
}

// ---- GEMM: C[M][N] f16 = A[M][K] * B[N][K]^T + bias[N]
// A is f32 (converted during LDS staging) or f16. 128x128 tile per 256-thread
// WG, 4 waves each 64x64 (4x4 of 16x16x32 f16 MFMA).
template <typename AT>
__global__ __launch_bounds__(256) void k_gemm(
    const AT* __restrict__ A, const u16* __restrict__ Bm,
    const float* __restrict__ bias, u16* __restrict__ C,
    int M, int N, int K)
{
    __shared__ u16 As[128 * 40];   // 32 k + 8 pad per row (80B stride, 16B aligned)
    __shared__ u16 Bs[128 * 40];
    const int m0 = blockIdx.y * 128, n0 = blockIdx.x * 128;
    const int t = threadIdx.x;
    const int wave = t >> 6, lane = t & 63;
    const int wm = wave & 1, wn = wave >> 1;
    const int lr = lane & 15, lq = lane >> 4;
    f32x4 acc[4][4] = {};
    const int sr = t >> 1, sp = t & 1;  // staging: 2 threads per row, 16 elems each
    const AT*  gA = A  + (size_t)(m0 + sr) * K + sp * 16;
    const u16* gB = Bm + (size_t)(n0 + sr) * K + sp * 16;
    u16* sA = As + sr * 40 + sp * 16;
    u16* sB = Bs + sr * 40 + sp * 16;
    for (int kt = 0; kt < K; kt += 32) {
        uint4 av0, av1;
        if constexpr (sizeof(AT) == 4) {       // f32 A: load 16 floats, cvt to f16
            float4 a0 = ((const float4*)gA)[0], a1 = ((const float4*)gA)[1];
            float4 a2 = ((const float4*)gA)[2], a3 = ((const float4*)gA)[3];
            f16x8 lo, hi;
            lo[0]=(_Float16)a0.x; lo[1]=(_Float16)a0.y; lo[2]=(_Float16)a0.z; lo[3]=(_Float16)a0.w;
            lo[4]=(_Float16)a1.x; lo[5]=(_Float16)a1.y; lo[6]=(_Float16)a1.z; lo[7]=(_Float16)a1.w;
            hi[0]=(_Float16)a2.x; hi[1]=(_Float16)a2.y; hi[2]=(_Float16)a2.z; hi[3]=(_Float16)a2.w;
            hi[4]=(_Float16)a3.x; hi[5]=(_Float16)a3.y; hi[6]=(_Float16)a3.z; hi[7]=(_Float16)a3.w;
            av0 = __builtin_bit_cast(uint4, lo);
            av1 = __builtin_bit_cast(uint4, hi);
        } else {                               // f16 A: straight 32B
            av0 = ((const uint4*)gA)[0];
            av1 = ((const uint4*)gA)[1];
        }
        uint4 b0 = ((const uint4*)gB)[0], b1 = ((const uint4*)gB)[1];
        gA += 32; gB += 32;
        __syncthreads();
        ((uint4*)sA)[0] = av0; ((uint4*)sA)[1] = av1;
        ((uint4*)sB)[0] = b0;  ((uint4*)sB)[1] = b1;
        __syncthreads();
        f16x8 af[4], bf[4];
#pragma unroll
        for (int i = 0; i < 4; i++)
            af[i] = *(const f16x8*)(As + (wm * 64 + i * 16 + lr) * 40 + lq * 8);
#pragma unroll
        for (int j = 0; j < 4; j++)
            bf[j] = *(const f16x8*)(Bs + (wn * 64 + j * 16 + lr) * 40 + lq * 8);
#pragma unroll
        for (int i = 0; i < 4; i++)
#pragma unroll
            for (int j = 0; j < 4; j++)
                acc[i][j] = __builtin_amdgcn_mfma_f32_16x16x32_f16(af[i], bf[j], acc[i][j], 0, 0, 0);
    }
#pragma unroll
    for (int i = 0; i < 4; i++) {
        int row = m0 + wm * 64 + i * 16 + lq * 4;
#pragma unroll
        for (int j = 0; j < 4; j++) {
            int col = n0 + wn * 64 + j * 16 + lr;
            float bv = bias[col];
#pragma unroll
            for (int rr = 0; rr < 4; rr++) {
                _Float16 v = (_Float16)(acc[i][j][rr] + bv);
                C[(size_t)(row + rr) * N + col] = __builtin_bit_cast(u16, v);
            }
        }
    }
}

// ---- GRU recurrence: one workgroup per graph, 768 threads (one W_hh row each,
// full row held in 128 packed-f16 VGPRs). h broadcast from LDS each step.
// Carried state hp0/hp1 stays f32; f16 enters only via W (exact) and dot inputs.
__global__ __launch_bounds__(768, 3) void k_rec(
    const u16* __restrict__ gx,          // [N_NODES][768] f16 input gates (incl. b_ih)
    const uint4* __restrict__ wsw,       // swizzled f16 W_hh
    const float* __restrict__ bhh,       // [768] f32
    const int*   __restrict__ starts,    // [129]
    u32* __restrict__ hout,              // packed f16 h output [N_NODES][128] (layer 0) or null
    float* __restrict__ out)             // [128][256] f32 mean (layer 1) or null
{
    __shared__ float ghb[G3];
    __shared__ float gxb[G3];
    __shared__ uint4 hpk4[HIDDEN / 8];   // h packed as 128 half2 (32 uint4)
    const int g = blockIdx.x;
    const int tid = threadIdx.x;         // = gate row
    const int start = starts[g];
    const int len = starts[g + 1] - start;
    // register-resident weight row (coalesced fill thanks to swizzle)
    const uint4* wp = wsw + (size_t)(tid >> 6) * 2048 + (tid & 63);
    uint4 w[32];
#pragma unroll
    for (int i = 0; i < 32; i++) w[i] = wp[(size_t)i * 64];
    const float bh = bhh[tid];
    if (tid < 32) hpk4[tid] = make_uint4(0, 0, 0, 0);
    float hp0 = 0.f, hp1 = 0.f, hs0 = 0.f, hs1 = 0.f;
    const _Float16* gxrow = (const _Float16*)gx + (size_t)start * G3 + tid;
    __syncthreads();
    float gcur = (len > 0) ? (float)gxrow[0] : 0.f;
    for (int t = 0; t < len; ++t) {
        int tn = (t + 1 < len) ? t + 1 : t;
        float gnext = (float)gxrow[(size_t)tn * G3];   // prefetch next step's input gate
        float a0 = bh, a1 = 0.f, a2 = 0.f, a3 = 0.f;
#pragma unroll
        for (int i = 0; i < 32; i++) {
            uint4 hv = hpk4[i];                        // broadcast ds_read_b128
            a0 = __builtin_amdgcn_fdot2(__builtin_bit_cast(half2_t, w[i].x), __builtin_bit_cast(half2_t, hv.x), a0, false);
            a1 = __builtin_amdgcn_fdot2(__builtin_bit_cast(half2_t, w[i].y), __builtin_bit_cast(half2_t, hv.y), a1, false);
            a2 = __builtin_amdgcn_fdot2(__builtin_bit_cast(half2_t, w[i].z), __builtin_bit_cast(half2_t, hv.z), a2, false);
            a3 = __builtin_amdgcn_fdot2(__builtin_bit_cast(half2_t, w[i].w), __builtin_bit_cast(half2_t, hv.w), a3, false);
        }
        ghb[tid] = (a0 + a1) + (a2 + a3);              // gh[row] incl. b_hh
        gxb[tid] = gcur;
        __syncthreads();
        if (tid < HIDDEN / 2) {                        // gate math: 2 h-indices per thread
            int j = tid * 2;
            float r0 = sigf(gxb[j]       + ghb[j]);
            float z0 = sigf(gxb[j + 256] + ghb[j + 256]);
            float n0 = tanhfast(gxb[j + 512] + r0 * ghb[j + 512]);
            float h0 = (1.f - z0) * n0 + z0 * hp0;
            float r1 = sigf(gxb[j + 1]   + ghb[j + 1]);
            float z1 = sigf(gxb[j + 257] + ghb[j + 257]);
            float n1 = tanhfast(gxb[j + 513] + r1 * ghb[j + 513]);
            float h1 = (1.f - z1) * n1 + z1 * hp1;
            hp0 = h0; hp1 = h1; hs0 += h0; hs1 += h1;
            half2_t p; p.x = (_Float16)h0; p.y = (_Float16)h1;
            u32 pk = __builtin_bit_cast(u32, p);
            ((u32*)hpk4)[tid] = pk;
            if (hout) hout[(size_t)(start + t) * (HIDDEN / 2) + tid] = pk;
        }
        gcur = gnext;
        __syncthreads();
    }
    if (out && tid < HIDDEN / 2) {
        float inv = 1.f / (float)(len > 0 ? len : 1);
        out[g * HIDDEN + 2 * tid]     = hs0 * inv;     // f32 output
        out[g * HIDDEN + 2 * tid + 1] = hs1 * inv;
    }
}

extern "C" void kernel_launch(void* const* d_in, const int* in_sizes, int n_in,
                              void* d_out, int out_size, void* d_ws, size_t ws_size,
                              hipStream_t stream)
{
    // Inputs are float32 per the reference (R0-R3 forensics: only the
    // f32-in/f32-out story is consistent with all observed failures).
    const float* x     = (const float*)d_in[0];
    const int*   batch = (const int*)d_in[1];
    const float* Wih0  = (const float*)d_in[2];
    const float* Whh0  = (const float*)d_in[3];
    const float* bih0  = (const float*)d_in[4];
    const float* bhh0  = (const float*)d_in[5];
    const float* Wih1  = (const float*)d_in[6];
    const float* Whh1  = (const float*)d_in[7];
    const float* bih1  = (const float*)d_in[8];
    const float* bhh1  = (const float*)d_in[9];
    float* out = (float*)d_out;

    // Workspace ~135.5 MB (known-good from R2: no abort at this size)
    char* ws = (char*)d_ws;
    size_t o = 0;
    int*   starts = (int*)  (ws + o); o += 4096;
    u16*   wi0    = (u16*)  (ws + o); o += (size_t)G3 * IN_DIM * 2;      // 384 KB (f16 W_ih0)
    u16*   wi1    = (u16*)  (ws + o); o += (size_t)G3 * HIDDEN * 2;     // 384 KB (f16 W_ih1)
    uint4* wsw0   = (uint4*)(ws + o); o += (size_t)G3 * HIDDEN * 2;     // 384 KB
    uint4* wsw1   = (uint4*)(ws + o); o += (size_t)G3 * HIDDEN * 2;     // 384 KB
    u16*   h0     = (u16*)  (ws + o); o += (size_t)N_NODES * HIDDEN * 2; // 33.5 MB (f16)
    u16*   gxbuf  = (u16*)  (ws + o); o += (size_t)N_NODES * G3 * 2;     // 100.7 MB (f16, reused)

    k_starts<<<1, 256, 0, stream>>>(batch, starts, N_NODES, NGRAPH);
    k_cvt8<<<96, 256, 0, stream>>>(Wih0, wi0, G3 * IN_DIM);
    k_cvt8<<<96, 256, 0, stream>>>(Wih1, wi1, G3 * HIDDEN);
    k_swz<<<96, 256, 0, stream>>>(Whh0, wsw0);
    k_swz<<<96, 256, 0, stream>>>(Whh1, wsw1);

    // layer 0: gx0 = x*Wih0^T + bih0 (A staged f32->f16); rec -> h0 (f16)
    k_gemm<float><<<dim3(G3 / 128, N_NODES / 128), 256, 0, stream>>>(x, wi0, bih0, gxbuf, N_NODES, G3, IN_DIM);
    k_rec<<<NGRAPH, 768, 0, stream>>>(gxbuf, wsw0, bhh0, starts, (u32*)h0, (float*)nullptr);
    // layer 1: gx1 = h0*Wih1^T + bih1 (f16 MFMA); rec + masked mean -> out (f32)
    k_gemm<_Float16><<<dim3(G3 / 128, N_NODES / 128), 256, 0, stream>>>((const _Float16*)h0, wi1, bih1, gxbuf, N_NODES, G3, HIDDEN);
    k_rec<<<NGRAPH, 768, 0, stream>>>(gxbuf, wsw1, bhh1, starts, (u32*)nullptr, out);
}

// Round 5
// 1689.827 us; speedup vs baseline: 1.0205x; 1.0205x over previous
//
#include <hip/hip_runtime.h>
#include <hip/hip_bf16.h>

typedef _Float16 half2_t __attribute__((ext_vector_type(2)));
typedef _Float16 f16x8   __attribute__((ext_vector_type(8)));
typedef float    f32x4   __attribute__((ext_vector_type(4)));
typedef unsigned short u16;
typedef unsigned int   u32;

#define N_NODES 65536
#define IN_DIM  256
#define HIDDEN  256
#define G3      768     // 3*HIDDEN gate rows
#define NGRAPH  128

__device__ __forceinline__ float sigf(float x)    { return 1.f / (1.f + __expf(-x)); }
__device__ __forceinline__ float tanhfast(float x){ return 2.f / (1.f + __expf(-2.f * x)) - 1.f; }

// ---- per-graph starts via binary search on sorted batch (int32/int64 autodetect) ----
__global__ void k_starts(const int* __restrict__ batch, int* __restrict__ starts, int n, int ngraph) {
    int g = blockIdx.x * blockDim.x + threadIdx.x;
    if (g > ngraph) return;
    int stride = (batch[n - 1] == 0) ? 2 : 1;
    if (g == ngraph) { starts[g] = n; return; }
    int lo = 0, hi = n;
    while (lo < hi) { int mid = (lo + hi) >> 1; if (batch[(size_t)mid * stride] < g) lo = mid + 1; else hi = mid; }
    starts[g] = lo;
}

// ---- f32 -> f16 elementwise (n multiple of 8) ----
__global__ void k_cvt8(const float* __restrict__ s, u16* __restrict__ d, int n) {
    int t = blockIdx.x * 256 + threadIdx.x;
    int i = t * 8;
    if (i >= n) return;
    float4 a = ((const float4*)(s + i))[0];
    float4 b = ((const float4*)(s + i))[1];
    f16x8 o;
    o[0] = (_Float16)a.x; o[1] = (_Float16)a.y; o[2] = (_Float16)a.z; o[3] = (_Float16)a.w;
    o[4] = (_Float16)b.x; o[5] = (_Float16)b.y; o[6] = (_Float16)b.z; o[7] = (_Float16)b.w;
    *(f16x8*)(d + i) = o;
}

// ---- W_hh f32 [768][256] -> swizzled f16 chunks so k_rec's register fill is
// coalesced. chunk t = w*2048 + i*64 + l holds W_hh[row=64w+l][8i..8i+7]. ----
__global__ void k_swz(const float* __restrict__ W, uint4* __restrict__ out) {
    int t = blockIdx.x * 256 + threadIdx.x;
    if (t >= 24576) return;
    int l = t & 63, i = (t >> 6) & 31, w = t >> 11;
    int row = w * 64 + l, col = i * 8;
    const float* s = W + row * 256 + col;
    f16x8 o;
#pragma unroll
    for (int q = 0; q < 8; q++) o[q] = (_Float16)s[q];
    out[t] = __builtin_bit_cast(uint4, o);
}

// ---- GEMM: C[M][N] f16 = A[M][K] * B[N][K]^T + bias[N]
// A is f32 (converted during LDS staging) or f16. 128x128 tile per 256-thread
// WG, 4 waves each 64x64 (4x4 of 16x16x32 f16 MFMA).
template <typename AT>
__global__ __launch_bounds__(256) void k_gemm(
    const AT* __restrict__ A, const u16* __restrict__ Bm,
    const float* __restrict__ bias, u16* __restrict__ C,
    int M, int N, int K)
{
    __shared__ u16 As[128 * 40];   // 32 k + 8 pad per row (80B stride, 16B aligned)
    __shared__ u16 Bs[128 * 40];
    const int m0 = blockIdx.y * 128, n0 = blockIdx.x * 128;
    const int t = threadIdx.x;
    const int wave = t >> 6, lane = t & 63;
    const int wm = wave & 1, wn = wave >> 1;
    const int lr = lane & 15, lq = lane >> 4;
    f32x4 acc[4][4] = {};
    const int sr = t >> 1, sp = t & 1;  // staging: 2 threads per row, 16 elems each
    const AT*  gA = A  + (size_t)(m0 + sr) * K + sp * 16;
    const u16* gB = Bm + (size_t)(n0 + sr) * K + sp * 16;
    u16* sA = As + sr * 40 + sp * 16;
    u16* sB = Bs + sr * 40 + sp * 16;
    for (int kt = 0; kt < K; kt += 32) {
        uint4 av0, av1;
        if constexpr (sizeof(AT) == 4) {       // f32 A: load 16 floats, cvt to f16
            float4 a0 = ((const float4*)gA)[0], a1 = ((const float4*)gA)[1];
            float4 a2 = ((const float4*)gA)[2], a3 = ((const float4*)gA)[3];
            f16x8 lo, hi;
            lo[0]=(_Float16)a0.x; lo[1]=(_Float16)a0.y; lo[2]=(_Float16)a0.z; lo[3]=(_Float16)a0.w;
            lo[4]=(_Float16)a1.x; lo[5]=(_Float16)a1.y; lo[6]=(_Float16)a1.z; lo[7]=(_Float16)a1.w;
            hi[0]=(_Float16)a2.x; hi[1]=(_Float16)a2.y; hi[2]=(_Float16)a2.z; hi[3]=(_Float16)a2.w;
            hi[4]=(_Float16)a3.x; hi[5]=(_Float16)a3.y; hi[6]=(_Float16)a3.z; hi[7]=(_Float16)a3.w;
            av0 = __builtin_bit_cast(uint4, lo);
            av1 = __builtin_bit_cast(uint4, hi);
        } else {                               // f16 A: straight 32B
            av0 = ((const uint4*)gA)[0];
            av1 = ((const uint4*)gA)[1];
        }
        uint4 b0 = ((const uint4*)gB)[0], b1 = ((const uint4*)gB)[1];
        gA += 32; gB += 32;
        __syncthreads();
        ((uint4*)sA)[0] = av0; ((uint4*)sA)[1] = av1;
        ((uint4*)sB)[0] = b0;  ((uint4*)sB)[1] = b1;
        __syncthreads();
        f16x8 af[4], bf[4];
#pragma unroll
        for (int i = 0; i < 4; i++)
            af[i] = *(const f16x8*)(As + (wm * 64 + i * 16 + lr) * 40 + lq * 8);
#pragma unroll
        for (int j = 0; j < 4; j++)
            bf[j] = *(const f16x8*)(Bs + (wn * 64 + j * 16 + lr) * 40 + lq * 8);
#pragma unroll
        for (int i = 0; i < 4; i++)
#pragma unroll
            for (int j = 0; j < 4; j++)
                acc[i][j] = __builtin_amdgcn_mfma_f32_16x16x32_f16(af[i], bf[j], acc[i][j], 0, 0, 0);
    }
#pragma unroll
    for (int i = 0; i < 4; i++) {
        int row = m0 + wm * 64 + i * 16 + lq * 4;
#pragma unroll
        for (int j = 0; j < 4; j++) {
            int col = n0 + wn * 64 + j * 16 + lr;
            float bv = bias[col];
#pragma unroll
            for (int rr = 0; rr < 4; rr++) {
                _Float16 v = (_Float16)(acc[i][j][rr] + bv);
                C[(size_t)(row + rr) * N + col] = __builtin_bit_cast(u16, v);
            }
        }
    }
}

// ---- GRU recurrence: one workgroup per graph, 768 threads (one W_hh row each,
// full row held in 128 packed-f16 VGPRs, pinned via opaque asm so the compiler
// cannot sink the loads into the loop — R4's VGPR=84 showed it re-read W from
// L2 every step, 6 MB/step/XCD = 1.4 us/step). h broadcast from LDS each step.
__global__ __launch_bounds__(768, 3) void k_rec(
    const u16* __restrict__ gx,          // [N_NODES][768] f16 input gates (incl. b_ih)
    const uint4* __restrict__ wsw,       // swizzled f16 W_hh
    const float* __restrict__ bhh,       // [768] f32
    const int*   __restrict__ starts,    // [129]
    u16* __restrict__ hout,              // f16 h output [N_NODES][256] (layer 0) or null
    float* __restrict__ out)             // [128][256] f32 mean (layer 1) or null
{
    __shared__ float ghb[G3];
    __shared__ float gxb[G3];
    __shared__ uint4 hpk4[HIDDEN / 8];   // h packed as 256 f16 (32 uint4)
    const int g = blockIdx.x;
    const int tid = threadIdx.x;         // = gate row
    const int start = starts[g];
    const int len = starts[g + 1] - start;
    // register-resident weight row (coalesced fill thanks to swizzle)
    const uint4* wp = wsw + (size_t)(tid >> 6) * 2048 + (tid & 63);
    uint4 w[32];
#pragma unroll
    for (int i = 0; i < 32; i++) w[i] = wp[(size_t)i * 64];
    // pin: make values opaque so they can't be rematerialized from memory
#pragma unroll
    for (int i = 0; i < 32; i++)
        asm volatile("" : "+v"(w[i].x), "+v"(w[i].y), "+v"(w[i].z), "+v"(w[i].w));
    const float bh = bhh[tid];
    if (tid < 32) hpk4[tid] = make_uint4(0, 0, 0, 0);
    float hp = 0.f, hs = 0.f;            // carried h / running sum (threads < 256)
    const _Float16* gxrow = (const _Float16*)gx + (size_t)start * G3 + tid;
    u16* hrow = hout ? (hout + (size_t)start * HIDDEN + tid) : (u16*)nullptr;
    __syncthreads();
    float gcur = (len > 0) ? (float)gxrow[0] : 0.f;
    for (int t = 0; t < len; ++t) {
        int tn = (t + 1 < len) ? t + 1 : t;
        float gnext = (float)gxrow[(size_t)tn * G3];   // prefetch next step's input gate
        float a0 = bh, a1 = 0.f, a2 = 0.f, a3 = 0.f;
#pragma unroll
        for (int i = 0; i < 32; i++) {
            uint4 hv = hpk4[i];                        // broadcast ds_read_b128
            a0 = __builtin_amdgcn_fdot2(__builtin_bit_cast(half2_t, w[i].x), __builtin_bit_cast(half2_t, hv.x), a0, false);
            a1 = __builtin_amdgcn_fdot2(__builtin_bit_cast(half2_t, w[i].y), __builtin_bit_cast(half2_t, hv.y), a1, false);
            a2 = __builtin_amdgcn_fdot2(__builtin_bit_cast(half2_t, w[i].z), __builtin_bit_cast(half2_t, hv.z), a2, false);
            a3 = __builtin_amdgcn_fdot2(__builtin_bit_cast(half2_t, w[i].w), __builtin_bit_cast(half2_t, hv.w), a3, false);
        }
        ghb[tid] = (a0 + a1) + (a2 + a3);              // gh[row] incl. b_hh
        gxb[tid] = gcur;
        __syncthreads();
        if (tid < HIDDEN) {                            // gate math: 1 h-index per thread
            float r = sigf(gxb[tid]       + ghb[tid]);
            float z = sigf(gxb[tid + 256] + ghb[tid + 256]);
            float n = tanhfast(gxb[tid + 512] + r * ghb[tid + 512]);
            float h = (1.f - z) * n + z * hp;
            hp = h; hs += h;
            _Float16 ph = (_Float16)h;
            u16 pk = __builtin_bit_cast(u16, ph);
            ((u16*)hpk4)[tid] = pk;
            if (hrow) hrow[(size_t)t * HIDDEN] = pk;
        }
        gcur = gnext;
        __syncthreads();
    }
    if (out && tid < HIDDEN) {
        float inv = 1.f / (float)(len > 0 ? len : 1);
        out[g * HIDDEN + tid] = hs * inv;              // f32 output
    }
}

extern "C" void kernel_launch(void* const* d_in, const int* in_sizes, int n_in,
                              void* d_out, int out_size, void* d_ws, size_t ws_size,
                              hipStream_t stream)
{
    const float* x     = (const float*)d_in[0];
    const int*   batch = (const int*)d_in[1];
    const float* Wih0  = (const float*)d_in[2];
    const float* Whh0  = (const float*)d_in[3];
    const float* bih0  = (const float*)d_in[4];
    const float* bhh0  = (const float*)d_in[5];
    const float* Wih1  = (const float*)d_in[6];
    const float* Whh1  = (const float*)d_in[7];
    const float* bih1  = (const float*)d_in[8];
    const float* bhh1  = (const float*)d_in[9];
    float* out = (float*)d_out;

    // Workspace ~135.5 MB
    char* ws = (char*)d_ws;
    size_t o = 0;
    int*   starts = (int*)  (ws + o); o += 4096;
    u16*   wi0    = (u16*)  (ws + o); o += (size_t)G3 * IN_DIM * 2;      // 384 KB (f16 W_ih0)
    u16*   wi1    = (u16*)  (ws + o); o += (size_t)G3 * HIDDEN * 2;     // 384 KB (f16 W_ih1)
    uint4* wsw0   = (uint4*)(ws + o); o += (size_t)G3 * HIDDEN * 2;     // 384 KB
    uint4* wsw1   = (uint4*)(ws + o); o += (size_t)G3 * HIDDEN * 2;     // 384 KB
    u16*   h0     = (u16*)  (ws + o); o += (size_t)N_NODES * HIDDEN * 2; // 33.5 MB (f16)
    u16*   gxbuf  = (u16*)  (ws + o); o += (size_t)N_NODES * G3 * 2;     // 100.7 MB (f16, reused)

    k_starts<<<1, 256, 0, stream>>>(batch, starts, N_NODES, NGRAPH);
    k_cvt8<<<96, 256, 0, stream>>>(Wih0, wi0, G3 * IN_DIM);
    k_cvt8<<<96, 256, 0, stream>>>(Wih1, wi1, G3 * HIDDEN);
    k_swz<<<96, 256, 0, stream>>>(Whh0, wsw0);
    k_swz<<<96, 256, 0, stream>>>(Whh1, wsw1);

    // layer 0: gx0 = x*Wih0^T + bih0 (A staged f32->f16); rec -> h0 (f16)
    k_gemm<float><<<dim3(G3 / 128, N_NODES / 128), 256, 0, stream>>>(x, wi0, bih0, gxbuf, N_NODES, G3, IN_DIM);
    k_rec<<<NGRAPH, 768, 0, stream>>>(gxbuf, wsw0, bhh0, starts, h0, (float*)nullptr);
    // layer 1: gx1 = h0*Wih1^T + bih1 (f16 MFMA); rec + masked mean -> out (f32)
    k_gemm<_Float16><<<dim3(G3 / 128, N_NODES / 128), 256, 0, stream>>>((const _Float16*)h0, wi1, bih1, gxbuf, N_NODES, G3, HIDDEN);
    k_rec<<<NGRAPH, 768, 0, stream>>>(gxbuf, wsw1, bhh1, starts, (u16*)nullptr, out);
}